// Round 1
// baseline (137.643 us; speedup 1.0000x reference)
//
#include <hip/hip_runtime.h>
#include <math.h>

#define NB    16      // batch
#define NTOK  4096    // N = 64*64
#define DIM   128
#define NE    8
#define HID   512
#define NOUT  128
#define NEXP  128     // expert blocks: 16 batches x 8 token positions
#define NGATE 512     // gate blocks: 128 contiguous tokens each

typedef float f4 __attribute__((ext_vector_type(4)));

// Cross-XCD handshake state. Device globals are zero-initialized at module
// load; the invariant "cnt1 == cnt2 == 0 at every kernel_launch boundary"
// is restored by the last expert block each call, so graph replay is safe
// and nothing depends on (poisoned) d_ws.
__device__ unsigned int g_hit[NGATE];   // per-gate-block expert-hit byte
__device__ float        g_s0[NB * NE];  // softmax score of expert 0, n<8
__device__ int          g_cnt1 = 0;     // gate blocks done
__device__ int          g_cnt2 = 0;     // expert blocks done

// One fused kernel, 640 blocks:
//   blocks 0..127   : expert-0 MixFFN for row (b,w) — gate-independent part
//                     runs CONCURRENTLY with gating; then waits on g_cnt1,
//                     applies the gate scale, stores its 128-float row.
//   blocks 128..639 : gating for 128 tokens each + zero-fill of out
//                     (skipping the 128 expert rows -> exactly-once writes,
//                     no cross-XCD writeback race), publish hit/s0, count up.
// Deadlock-safe: 128 spinners < 256 min-resident blocks, gate always flows.
__global__ __launch_bounds__(256) void moe_fused(
    const float* __restrict__ x,     // (16,4096,128) f32
    const float* __restrict__ wg,    // (128,8)
    const float* __restrict__ bg,    // (8)
    const float* __restrict__ W1,    // (8,128,512) -> expert 0 slice
    const float* __restrict__ B1,    // (8,512)
    const float* __restrict__ Wd,    // (8,3,3,1,512)
    const float* __restrict__ Bd,    // (8,512)
    const float* __restrict__ W2,    // (8,512,128) -> expert 0 slice
    const float* __restrict__ B2,    // (8,128)
    float*       __restrict__ out)   // (16,4096,128) f32
{
    int tid = threadIdx.x;

    if (blockIdx.x >= NEXP) {
        // ======================= gate phase =======================
        int gb = blockIdx.x - NEXP;
        __shared__ f4 lw4[NE][DIM / 4];    // wg transposed
        __shared__ float lbg[NE];
        __shared__ unsigned int lmask;

        {   // stage wg transposed (one f4 per thread)
            int e = tid >> 5, s = tid & 31, d0 = s * 4;
            f4 w;
            w.x = wg[(d0 + 0) * NE + e];
            w.y = wg[(d0 + 1) * NE + e];
            w.z = wg[(d0 + 2) * NE + e];
            w.w = wg[(d0 + 3) * NE + e];
            lw4[e][s] = w;
        }
        if (tid < NE) lbg[tid] = bg[tid];
        if (tid == 0) lmask = 0u;
        __syncthreads();

        int sub  = tid & 7;       // lane-within-token
        int tgrp = tid >> 3;      // token-within-chunk (0..31)

        // hoist this lane's weight slice into VGPRs
        f4 wv[NE][4];
        #pragma unroll
        for (int e = 0; e < NE; e++)
            #pragma unroll
            for (int k = 0; k < 4; k++) wv[e][k] = lw4[e][sub + 8 * k];

        const f4* x4 = (const f4*)x;
        f4* o4 = (f4*)out;

        #pragma unroll 2
        for (int it = 0; it < 4; it++) {
            int tok = (gb << 7) + (it << 5) + tgrp;   // 0..65535
            int b   = tok >> 12;
            int n   = tok & 4095;
            size_t base = (size_t)tok * 32 + sub;

            // zero-fill first (overlaps load latency). Skip the 128 rows
            // with n<8: those are written exactly once by expert blocks.
            if (n >= 8) {
                f4 zz = {0.f, 0.f, 0.f, 0.f};
                __builtin_nontemporal_store(zz, o4 + base);
                __builtin_nontemporal_store(zz, o4 + base + 8);
                __builtin_nontemporal_store(zz, o4 + base + 16);
                __builtin_nontemporal_store(zz, o4 + base + 24);
            }

            f4 xv0 = __builtin_nontemporal_load(x4 + base);
            f4 xv1 = __builtin_nontemporal_load(x4 + base + 8);
            f4 xv2 = __builtin_nontemporal_load(x4 + base + 16);
            f4 xv3 = __builtin_nontemporal_load(x4 + base + 24);

            float z[NE];
            #pragma unroll
            for (int e = 0; e < NE; e++) {
                z[e] = xv0.x * wv[e][0].x + xv0.y * wv[e][0].y
                     + xv0.z * wv[e][0].z + xv0.w * wv[e][0].w
                     + xv1.x * wv[e][1].x + xv1.y * wv[e][1].y
                     + xv1.z * wv[e][1].z + xv1.w * wv[e][1].w
                     + xv2.x * wv[e][2].x + xv2.y * wv[e][2].y
                     + xv2.z * wv[e][2].z + xv2.w * wv[e][2].w
                     + xv3.x * wv[e][3].x + xv3.y * wv[e][3].y
                     + xv3.z * wv[e][3].z + xv3.w * wv[e][3].w;
            }

            // butterfly sum across the 8 lanes of this token
            #pragma unroll
            for (int off = 1; off <= 4; off <<= 1) {
                #pragma unroll
                for (int e = 0; e < NE; e++) z[e] += __shfl_xor(z[e], off);
            }

            if (sub == 0) {
                float zf[NE];
                #pragma unroll
                for (int e = 0; e < NE; e++) zf[e] = z[e] + lbg[e];

                int am = 0;
                float mz = zf[0];
                #pragma unroll
                for (int e = 1; e < NE; e++) {
                    if (zf[e] > mz) { mz = zf[e]; am = e; }
                }
                atomicOr(&lmask, 1u << am);   // LDS atomic

                if (n < 8) {                  // softmax score for expert 0
                    float ssum = 0.f;
                    #pragma unroll
                    for (int e = 0; e < NE; e++) ssum += expf(zf[e] - mz);
                    __hip_atomic_store(&g_s0[b * NE + n], expf(zf[0] - mz) / ssum,
                                       __ATOMIC_RELAXED, __HIP_MEMORY_SCOPE_AGENT);
                }
            }
        }

        __syncthreads();
        if (tid == 0) {
            __hip_atomic_store(&g_hit[gb], lmask,
                               __ATOMIC_RELAXED, __HIP_MEMORY_SCOPE_AGENT);
            __hip_atomic_fetch_add(&g_cnt1, 1,
                                   __ATOMIC_RELEASE, __HIP_MEMORY_SCOPE_AGENT);
        }
        return;
    }

    // ======================= expert phase =======================
    int b = blockIdx.x >> 3;
    int w = blockIdx.x & 7;      // token position = gate index

    __shared__ float4 xs4[6][32];     //  3 KB: xs[p][d], p = row*3 + ci
    __shared__ float4 redb[128][6];   // 12 KB: k-half-1 fc1 partials
    __shared__ float  gls[HID];       //  2 KB
    __shared__ float  red2[256];
    __shared__ unsigned int hmred[128];
    __shared__ float  svred[NB];
    __shared__ float  gate_s;

    // stage x rows (row 0..1) x (cols w-1..w+1): 192 float4, coalesced.
    if (tid < 192) {
        int p = tid >> 5, dq = tid & 31;
        int row = p / 3, ci = p % 3;
        int col = w - 1 + ci;
        if (col < 0) col = 0;
        xs4[p][dq] = ((const float4*)x)[((size_t)b * NTOK + row * 64 + col) * 32 + dq];
    }
    __syncthreads();

    // fc1: K-split over kh; thread (q = tid&127, kh = tid>>7)
    int q  = tid & 127;
    int kh = tid >> 7;
    float4 acc[6];
    #pragma unroll
    for (int p = 0; p < 6; p++) acc[p] = make_float4(0.f, 0.f, 0.f, 0.f);

    const float4* W14 = (const float4*)W1;   // [128][128] float4 view
    #pragma unroll 4
    for (int s = 0; s < 16; s++) {
        int d0 = kh * 64 + s * 4;
        float4 wv0 = W14[(size_t)(d0 + 0) * 128 + q];
        float4 wv1 = W14[(size_t)(d0 + 1) * 128 + q];
        float4 wv2 = W14[(size_t)(d0 + 2) * 128 + q];
        float4 wv3 = W14[(size_t)(d0 + 3) * 128 + q];
        #pragma unroll
        for (int p = 0; p < 6; p++) {
            float4 xv = xs4[p][kh * 16 + s];
            acc[p].x += xv.x * wv0.x + xv.y * wv1.x + xv.z * wv2.x + xv.w * wv3.x;
            acc[p].y += xv.x * wv0.y + xv.y * wv1.y + xv.z * wv2.y + xv.w * wv3.y;
            acc[p].z += xv.x * wv0.z + xv.y * wv1.z + xv.z * wv2.z + xv.w * wv3.z;
            acc[p].w += xv.x * wv0.w + xv.y * wv1.w + xv.z * wv2.w + xv.w * wv3.w;
        }
    }

    if (kh == 1) {
        #pragma unroll
        for (int p = 0; p < 6; p++) redb[q][p] = acc[p];
    }
    __syncthreads();

    // dwconv + biases + exact gelu on the low-half threads
    if (kh == 0) {
        #pragma unroll
        for (int p = 0; p < 6; p++) {
            float4 r = redb[q][p];
            acc[p].x += r.x; acc[p].y += r.y; acc[p].z += r.z; acc[p].w += r.w;
        }
        float4 b1 = ((const float4*)B1)[q];
        float4 y  = ((const float4*)Bd)[q];
        #pragma unroll
        for (int ci = 0; ci < 3; ci++) {
            int col = w - 1 + ci;
            if (col < 0) continue;   // SAME-padding tap
            float4 wda = ((const float4*)Wd)[(3 + ci) * 128 + q];  // kh=1 -> row 0
            float4 wdb = ((const float4*)Wd)[(6 + ci) * 128 + q];  // kh=2 -> row 1
            float4 a0 = acc[ci];
            float4 a1 = acc[3 + ci];
            y.x += (a0.x + b1.x) * wda.x + (a1.x + b1.x) * wdb.x;
            y.y += (a0.y + b1.y) * wda.y + (a1.y + b1.y) * wdb.y;
            y.z += (a0.z + b1.z) * wda.z + (a1.z + b1.z) * wdb.z;
            y.w += (a0.w + b1.w) * wda.w + (a1.w + b1.w) * wdb.w;
        }
        const float kk = 0.70710678118654752f;
        float4 g;
        g.x = 0.5f * y.x * (1.0f + erff(y.x * kk));
        g.y = 0.5f * y.y * (1.0f + erff(y.y * kk));
        g.z = 0.5f * y.z * (1.0f + erff(y.z * kk));
        g.w = 0.5f * y.w * (1.0f + erff(y.w * kk));
        ((float4*)gls)[q] = g;
    }
    __syncthreads();

    // fc2: 2-way c-split, lane = output channel, 32 W2 loads in flight
    int o    = tid & 127;
    int half = tid >> 7;
    const float* wp = W2 + (size_t)(half * 256) * NOUT + o;
    const float4* gp = (const float4*)&gls[half * 256];
    float a = 0.f;
    #pragma unroll
    for (int cb = 0; cb < 256; cb += 32) {
        float wvv[32];
        #pragma unroll
        for (int k2 = 0; k2 < 32; k2++) wvv[k2] = wp[(size_t)(cb + k2) * NOUT];
        #pragma unroll
        for (int k2 = 0; k2 < 32; k2 += 4) {
            float4 g = gp[(cb + k2) >> 2];
            a += g.x * wvv[k2] + g.y * wvv[k2 + 1] + g.z * wvv[k2 + 2] + g.w * wvv[k2 + 3];
        }
    }
    red2[tid] = a;
    __syncthreads();

    // ---- wait for all 512 gate blocks (cross-XCD handshake) ----
    if (tid == 0) {
        while (__hip_atomic_load(&g_cnt1, __ATOMIC_RELAXED,
                                 __HIP_MEMORY_SCOPE_AGENT) < NGATE)
            __builtin_amdgcn_s_sleep(8);
        (void)__hip_atomic_load(&g_cnt1, __ATOMIC_ACQUIRE,
                                __HIP_MEMORY_SCOPE_AGENT);
    }
    __syncthreads();

    // fold the 512 hit bytes -> per-batch mask (parallel, coherent loads)
    if (tid < 128) {
        unsigned int m = 0;
        #pragma unroll
        for (int i = 0; i < 4; i++)
            m |= __hip_atomic_load(&g_hit[tid * 4 + i], __ATOMIC_RELAXED,
                                   __HIP_MEMORY_SCOPE_AGENT);
        hmred[tid] = m;
    }
    __syncthreads();
    if (tid < NB) {
        unsigned int m = 0;
        #pragma unroll
        for (int i = 0; i < 8; i++) m |= hmred[tid * 8 + i];
        float v = 0.f;
        if ((m >> w) & 1u)
            v = __hip_atomic_load(&g_s0[tid * NE + w], __ATOMIC_RELAXED,
                                  __HIP_MEMORY_SCOPE_AGENT);
        svred[tid] = v;
    }
    __syncthreads();
    if (tid == 0) {
        float denom = 1e-6f;
        #pragma unroll
        for (int bb = 0; bb < NB; bb++) denom += svred[bb];
        gate_s = 16.0f * svred[b] / denom;
    }
    __syncthreads();

    if (tid < 128) {
        out[((size_t)b * NTOK + w) * NOUT + o] =
            (red2[tid] + red2[tid + 128] + B2[o]) * gate_s;
    }

    // restore handshake invariant for the next (graph-replayed) call
    __syncthreads();
    if (tid == 0) {
        int v = __hip_atomic_fetch_add(&g_cnt2, 1, __ATOMIC_ACQ_REL,
                                       __HIP_MEMORY_SCOPE_AGENT);
        if (v == NEXP - 1) {
            __hip_atomic_store(&g_cnt1, 0, __ATOMIC_RELAXED, __HIP_MEMORY_SCOPE_AGENT);
            __hip_atomic_store(&g_cnt2, 0, __ATOMIC_RELAXED, __HIP_MEMORY_SCOPE_AGENT);
        }
    }
}

extern "C" void kernel_launch(void* const* d_in, const int* in_sizes, int n_in,
                              void* d_out, int out_size, void* d_ws, size_t ws_size,
                              hipStream_t stream) {
    const float* x  = (const float*)d_in[0];
    // d_in[1] = H, d_in[2] = W (ints) — fixed 64x64, hard-coded
    const float* wg = (const float*)d_in[3];
    const float* bg = (const float*)d_in[4];
    const float* W1 = (const float*)d_in[5];
    const float* B1 = (const float*)d_in[6];
    const float* Wd = (const float*)d_in[7];
    const float* Bd = (const float*)d_in[8];
    const float* W2 = (const float*)d_in[9];
    const float* B2 = (const float*)d_in[10];
    (void)d_ws; (void)ws_size; (void)in_sizes; (void)n_in; (void)out_size;

    moe_fused<<<NEXP + NGATE, 256, 0, stream>>>(
        x, wg, bg, W1, B1, Wd, Bd, W2, B2, (float*)d_out);
}

// Round 2
// 121.671 us; speedup vs baseline: 1.1313x; 1.1313x over previous
//
#include <hip/hip_runtime.h>
#include <math.h>

#define NB    16      // batch
#define NTOK  4096    // N = 64*64
#define DIM   128
#define NE    8
#define HID   512
#define NOUT  128
#define GBLK  2048    // gate blocks: each covers 32 contiguous tokens

typedef float f4 __attribute__((ext_vector_type(4)));

// ws layout (all bytes read are written first each call):
//   s0      float[16*8]    @ 0    (512 B)
//   hitpart byte[2048]     @ 512  (2048 B, one per gate block)

// Gate: 8 lanes per token, ONE token-group per block (32 tokens), weights
// read directly from LDS inside the FMA loop (no VGPR hoist) -> ~50 VGPR,
// 2048 blocks = 8 blocks/CU schedulable -> full occupancy, deep VMEM queue.
// Zero-fill of the output rows is issued first (overlaps load latency);
// the expert kernel later overwrites the 128 nonzero rows (stream-serial).
__global__ __launch_bounds__(256) void gate_kernel(
    const f4* __restrict__ x,            // (16,4096,128) f32 as float4
    const float* __restrict__ wg,        // (128,8)
    const float* __restrict__ bg,        // (8)
    float* __restrict__ s0,              // ws (16,8)
    unsigned char* __restrict__ hitpart, // ws (2048) one byte per block
    f4* __restrict__ out)                // (16,4096,128) f32
{
    __shared__ f4 lw4[NE][DIM / 4];  // 4 KB: wg transposed
    __shared__ float lbg[NE];
    __shared__ unsigned int lmask;

    int tid = threadIdx.x;
    {   // stage wg transposed (one float4 per thread)
        int e = tid >> 5, s = tid & 31, d0 = s * 4;
        f4 w;
        w.x = wg[(d0 + 0) * NE + e];
        w.y = wg[(d0 + 1) * NE + e];
        w.z = wg[(d0 + 2) * NE + e];
        w.w = wg[(d0 + 3) * NE + e];
        lw4[e][s] = w;
    }
    if (tid < NE) lbg[tid] = bg[tid];
    if (tid == 0) lmask = 0u;
    __syncthreads();

    int sub  = tid & 7;       // lane-within-token
    int tgrp = tid >> 3;      // token-within-block (0..31)

    int tok = (blockIdx.x << 5) + tgrp;   // 0..65535
    int b   = tok >> 12;
    int n   = tok & 4095;
    size_t base = (size_t)tok * 32 + sub;

    // zero-fill first: independent stores overlap the load latency
    f4 zz = {0.f, 0.f, 0.f, 0.f};
    out[base]      = zz;
    out[base + 8]  = zz;
    out[base + 16] = zz;
    out[base + 24] = zz;

    f4 xv0 = x[base];
    f4 xv1 = x[base + 8];
    f4 xv2 = x[base + 16];
    f4 xv3 = x[base + 24];

    float z[NE];
    #pragma unroll
    for (int e = 0; e < NE; e++) z[e] = 0.f;

    // weights straight from LDS: lanes 0..7 hit 8 consecutive 16B slots
    // (conflict-free b128), lane-groups 8.. broadcast the same addresses.
    #pragma unroll
    for (int k = 0; k < 4; k++) {
        f4 xv = (k == 0) ? xv0 : (k == 1) ? xv1 : (k == 2) ? xv2 : xv3;
        #pragma unroll
        for (int e = 0; e < NE; e++) {
            f4 w = lw4[e][sub + 8 * k];
            z[e] += xv.x * w.x + xv.y * w.y + xv.z * w.z + xv.w * w.w;
        }
    }

    // butterfly sum across the 8 lanes of this token (xor 1,2,4)
    #pragma unroll
    for (int off = 1; off <= 4; off <<= 1) {
        #pragma unroll
        for (int e = 0; e < NE; e++) z[e] += __shfl_xor(z[e], off);
    }

    if (sub == 0) {
        float zf[NE];
        #pragma unroll
        for (int e = 0; e < NE; e++) zf[e] = z[e] + lbg[e];

        int am = 0;
        float mz = zf[0];
        #pragma unroll
        for (int e = 1; e < NE; e++) {
            if (zf[e] > mz) { mz = zf[e]; am = e; }
        }
        atomicOr(&lmask, 1u << am);   // LDS atomic

        if (n < 8) {                   // softmax score for expert 0
            float s = 0.f;
            #pragma unroll
            for (int e = 0; e < NE; e++) s += expf(zf[e] - mz);
            s0[b * NE + n] = expf(zf[0] - mz) / s;
        }
    }

    __syncthreads();
    if (tid == 0) hitpart[blockIdx.x] = (unsigned char)lmask;
}

// Fused expert-0 MixFFN + gate scale for the 128 nonzero output rows.
// grid = 16 batches x 8 token positions (w), 256 threads.
__global__ __launch_bounds__(256) void expert_kernel(
    const float* __restrict__ x,
    const float* __restrict__ W1,   // (8,128,512) -> expert 0 slice
    const float* __restrict__ B1,   // (8,512)
    const float* __restrict__ Wd,   // (8,3,3,1,512)
    const float* __restrict__ Bd,   // (8,512)
    const float* __restrict__ W2,   // (8,512,128) -> expert 0 slice
    const float* __restrict__ B2,   // (8,128)
    const float* __restrict__ s0,
    const unsigned char* __restrict__ hitpart,
    float* __restrict__ out)
{
    __shared__ float4 xs4[6][32];     //  3 KB: xs[p][d], p = row*3 + ci
    __shared__ float4 redb[128][6];   // 12 KB: k-half-1 fc1 partials
    __shared__ float gls[HID];        //  2 KB
    __shared__ float red2[256];
    __shared__ unsigned int hm[NB];
    __shared__ float gate_s;

    int b = blockIdx.x >> 3;
    int w = blockIdx.x & 7;      // token position = gate index
    int tid = threadIdx.x;

    // hit bitmask (2048 B = 128 uint4): 8 uint4 per batch, no atomics
    if (tid < NB) {
        const uint4* hp = (const uint4*)hitpart;
        unsigned int m = 0;
        #pragma unroll
        for (int i = 0; i < 8; i++) {
            uint4 v = hp[tid * 8 + i];
            m |= v.x | v.y | v.z | v.w;
        }
        m |= m >> 16; m |= m >> 8; m &= 0xffu;
        hm[tid] = m;
    }

    // stage x rows (row 0..1) x (cols w-1..w+1): 192 float4, coalesced.
    // col<0 clamps to 0 (garbage values; dwconv skips that tap).
    if (tid < 192) {
        int p = tid >> 5, dq = tid & 31;
        int row = p / 3, ci = p % 3;
        int col = w - 1 + ci;
        if (col < 0) col = 0;
        xs4[p][dq] = ((const float4*)x)[((size_t)b * NTOK + row * 64 + col) * 32 + dq];
    }
    __syncthreads();

    if (tid == 0) {
        float denom = 1e-6f, mine = 0.f;
        for (int bb = 0; bb < NB; bb++) {
            float v = ((hm[bb] >> w) & 1u) ? s0[bb * NE + w] : 0.f;
            denom += v;
            if (bb == b) mine = v;
        }
        gate_s = 16.0f * mine / denom;
    }

    // fc1: acc[p][j] = sum_d xs[p][d] * W1[d][4q+j], K-split over kh
    int q  = tid & 127;       // float4-column: channels 4q..4q+3
    int kh = tid >> 7;        // 0/1: d in [kh*64, kh*64+64)
    float4 acc[6];
    #pragma unroll
    for (int p = 0; p < 6; p++) acc[p] = make_float4(0.f, 0.f, 0.f, 0.f);

    const float4* W14 = (const float4*)W1;   // [128][128] float4 view
    #pragma unroll 4
    for (int s = 0; s < 16; s++) {
        int d0 = kh * 64 + s * 4;
        float4 wv0 = W14[(size_t)(d0 + 0) * 128 + q];
        float4 wv1 = W14[(size_t)(d0 + 1) * 128 + q];
        float4 wv2 = W14[(size_t)(d0 + 2) * 128 + q];
        float4 wv3 = W14[(size_t)(d0 + 3) * 128 + q];
        #pragma unroll
        for (int p = 0; p < 6; p++) {
            float4 xv = xs4[p][kh * 16 + s];
            acc[p].x += xv.x * wv0.x + xv.y * wv1.x + xv.z * wv2.x + xv.w * wv3.x;
            acc[p].y += xv.x * wv0.y + xv.y * wv1.y + xv.z * wv2.y + xv.w * wv3.y;
            acc[p].z += xv.x * wv0.z + xv.y * wv1.z + xv.z * wv2.z + xv.w * wv3.z;
            acc[p].w += xv.x * wv0.w + xv.y * wv1.w + xv.z * wv2.w + xv.w * wv3.w;
        }
    }

    // reduce the two k-halves via LDS
    if (kh == 1) {
        #pragma unroll
        for (int p = 0; p < 6; p++) redb[q][p] = acc[p];
    }
    __syncthreads();

    // dwconv + biases + exact gelu on the low-half threads (4 channels each)
    if (kh == 0) {
        #pragma unroll
        for (int p = 0; p < 6; p++) {
            float4 r = redb[q][p];
            acc[p].x += r.x; acc[p].y += r.y; acc[p].z += r.z; acc[p].w += r.w;
        }
        float4 b1 = ((const float4*)B1)[q];
        float4 y  = ((const float4*)Bd)[q];
        #pragma unroll
        for (int ci = 0; ci < 3; ci++) {
            int col = w - 1 + ci;
            if (col < 0) continue;   // SAME-padding: h1 entry is 0, skip tap
            float4 wda = ((const float4*)Wd)[(3 + ci) * 128 + q];  // kh=1 -> row 0
            float4 wdb = ((const float4*)Wd)[(6 + ci) * 128 + q];  // kh=2 -> row 1
            float4 a0 = acc[ci];       // row 0, this col
            float4 a1 = acc[3 + ci];   // row 1, this col
            y.x += (a0.x + b1.x) * wda.x + (a1.x + b1.x) * wdb.x;
            y.y += (a0.y + b1.y) * wda.y + (a1.y + b1.y) * wdb.y;
            y.z += (a0.z + b1.z) * wda.z + (a1.z + b1.z) * wdb.z;
            y.w += (a0.w + b1.w) * wda.w + (a1.w + b1.w) * wdb.w;
        }
        const float k = 0.70710678118654752f;
        float4 g;
        g.x = 0.5f * y.x * (1.0f + erff(y.x * k));
        g.y = 0.5f * y.y * (1.0f + erff(y.y * k));
        g.z = 0.5f * y.z * (1.0f + erff(y.z * k));
        g.w = 0.5f * y.w * (1.0f + erff(y.w * k));
        ((float4*)gls)[q] = g;
    }
    __syncthreads();

    // fc2: 2-way c-split, lane = output channel, 32 W2 loads in flight
    int o    = tid & 127;
    int half = tid >> 7;
    const float* wp = W2 + (size_t)(half * 256) * NOUT + o;
    const float4* gp = (const float4*)&gls[half * 256];
    float a = 0.f;
    #pragma unroll
    for (int cb = 0; cb < 256; cb += 32) {
        float wv[32];
        #pragma unroll
        for (int k2 = 0; k2 < 32; k2++) wv[k2] = wp[(size_t)(cb + k2) * NOUT];
        #pragma unroll
        for (int k2 = 0; k2 < 32; k2 += 4) {
            float4 g = gp[(cb + k2) >> 2];
            a += g.x * wv[k2] + g.y * wv[k2 + 1] + g.z * wv[k2 + 2] + g.w * wv[k2 + 3];
        }
    }
    red2[tid] = a;
    __syncthreads();
    if (tid < 128) {
        out[((size_t)b * NTOK + w) * NOUT + o] =
            (red2[tid] + red2[tid + 128] + B2[o]) * gate_s;
    }
}

extern "C" void kernel_launch(void* const* d_in, const int* in_sizes, int n_in,
                              void* d_out, int out_size, void* d_ws, size_t ws_size,
                              hipStream_t stream) {
    const float* x  = (const float*)d_in[0];
    // d_in[1] = H, d_in[2] = W (ints) — fixed 64x64, hard-coded
    const float* wg = (const float*)d_in[3];
    const float* bg = (const float*)d_in[4];
    const float* W1 = (const float*)d_in[5];
    const float* B1 = (const float*)d_in[6];
    const float* Wd = (const float*)d_in[7];
    const float* Bd = (const float*)d_in[8];
    const float* W2 = (const float*)d_in[9];
    const float* B2 = (const float*)d_in[10];

    float* s0              = (float*)d_ws;
    unsigned char* hitpart = (unsigned char*)d_ws + 512;

    gate_kernel<<<GBLK, 256, 0, stream>>>(
        (const f4*)x, wg, bg, s0, hitpart, (f4*)d_out);
    expert_kernel<<<NB * 8, 256, 0, stream>>>(
        x, W1, B1, Wd, Bd, W2, B2, s0, hitpart, (float*)d_out);
}